// Round 7
// baseline (269.950 us; speedup 1.0000x reference)
//
#include <hip/hip_runtime.h>
#include <math.h>

// Problem constants (B=64, P=2, H=512, W=512)
#define HH 512
#define WW 512
#define BP 128                  // B*P pairs
#define PLANE (HH * WW)         // 262144 elems per (b,p) plane
#define SEG2 32                 // segments per pair
#define SEG_FLOATS 8192         // floats per segment (32 KB)
#define NPART2 (BP * SEG2)      // 4096 partial records per quantity

// ws float layout: [0,4096) sum, [4096,8192) sumx, [8192,12288) sumy,
// [12288,16384) maxval ; ints at float offset [16384,20480) maxidx. 80 KiB.

// R11: split-path streaming. Post-NT the kernel is service-rate limited at
// 3.5 TB/s read (77 us) independent of request depth (R8=R9=R10). Evidence
// from R0-R7: FETCH was exactly half (134 MB) -> the harness fills leave
// both arrays IC-resident and the IC read path can serve them, but all-NT
// routes everything through HBM and leaves the IC path idle. This round:
// input stream NT (HBM path, no IC disturbance), target stream cacheable
// (IC-hit path, stays resident since nothing else allocates), interleaved
// by block parity so both paths are loaded concurrently. If the paths are
// independent, bandwidths add: ~45-60 us. If unchanged: 3.5 TB/s is the
// read fabric cap -> roofline.
typedef float f4 __attribute__((ext_vector_type(4)));

__global__ __launch_bounds__(256) void dsnt_partial(
    const float* __restrict__ inp, const float* __restrict__ tgt,
    float* __restrict__ wsf, int* __restrict__ wsi)
{
    const int tid  = threadIdx.x;
    const int blk  = blockIdx.x;
    const int lane = tid & 63, wid = tid >> 6;
    const float inv = 1.0f / 512.0f;

    __shared__ float rs[4], rsx[4], rsy[4], rmv[4];
    __shared__ int   rmi[4];

    // Parity interleave: even blocks stream input (NT/HBM path), odd blocks
    // stream target (cacheable/IC path) -> both paths busy the whole kernel.
    const bool is_sm = ((blk & 1) == 0);
    const int  b2    = blk >> 1;          // 0..4095
    const int  pair  = b2 >> 5;
    const int  seg   = b2 & 31;
    const f4* __restrict__ gp =
        (const f4*)((is_sm ? inp : tgt) + (size_t)pair * PLANE + seg * SEG_FLOATS);
    const int segbase = seg * SEG_FLOATS;

    if (is_sm) {
        // ---- softmax partial sums, NT (HBM path) depth-4 pipeline ----
        float s = 0.0f, sx = 0.0f, sy = 0.0f;
#define SM_ACC(v, jj)                                                          \
        do {                                                                   \
            const int f = segbase + ((jj) * 256 + tid) * 4; /* %4==0 */        \
            const float yw  = (float)((f >> 9) + 1) * inv;                     \
            const float xw0 = (float)((f & 511) + 1) * inv;                    \
            const float e0 = __expf(v.x);                                      \
            const float e1 = __expf(v.y);                                      \
            const float e2 = __expf(v.z);                                      \
            const float e3 = __expf(v.w);                                      \
            const float es = e0 + e1 + e2 + e3;                                \
            s  += es;                                                          \
            sx += es * xw0 + inv * (e1 + 2.0f * e2 + 3.0f * e3);               \
            sy += es * yw;                                                     \
        } while (0)
        f4 c0 = __builtin_nontemporal_load(gp + 0 * 256 + tid);
        f4 c1 = __builtin_nontemporal_load(gp + 1 * 256 + tid);
        f4 c2 = __builtin_nontemporal_load(gp + 2 * 256 + tid);
        f4 c3 = __builtin_nontemporal_load(gp + 3 * 256 + tid);
        SM_ACC(c0, 0); c0 = __builtin_nontemporal_load(gp + 4 * 256 + tid);
        SM_ACC(c1, 1); c1 = __builtin_nontemporal_load(gp + 5 * 256 + tid);
        SM_ACC(c2, 2); c2 = __builtin_nontemporal_load(gp + 6 * 256 + tid);
        SM_ACC(c3, 3); c3 = __builtin_nontemporal_load(gp + 7 * 256 + tid);
        SM_ACC(c0, 4); SM_ACC(c1, 5); SM_ACC(c2, 6); SM_ACC(c3, 7);
#undef SM_ACC

#pragma unroll
        for (int off = 32; off > 0; off >>= 1) {
            s  += __shfl_down(s,  off, 64);
            sx += __shfl_down(sx, off, 64);
            sy += __shfl_down(sy, off, 64);
        }
        if (lane == 0) { rs[wid] = s; rsx[wid] = sx; rsy[wid] = sy; }
        __syncthreads();
        if (tid == 0) {
            float fs = rs[0], fsx = rsx[0], fsy = rsy[0];
#pragma unroll
            for (int k = 1; k < 4; ++k) { fs += rs[k]; fsx += rsx[k]; fsy += rsy[k]; }
            wsf[b2]              = fs;
            wsf[NPART2 + b2]     = fsx;
            wsf[2 * NPART2 + b2] = fsy;
        }
    } else {
        // ---- argmax partial over target, cacheable (IC-hit path) ----
        float mv = -1.0f;
        int   mi = 0;
#define AM_ACC(v, jj)                                                          \
        do {                                                                   \
            const int f = segbase + ((jj) * 256 + tid) * 4;                    \
            if (v.x > mv) { mv = v.x; mi = f; }                                \
            if (v.y > mv) { mv = v.y; mi = f + 1; }                            \
            if (v.z > mv) { mv = v.z; mi = f + 2; }                            \
            if (v.w > mv) { mv = v.w; mi = f + 3; }                            \
        } while (0)
        f4 t0 = gp[0 * 256 + tid];
        f4 t1 = gp[1 * 256 + tid];
        f4 t2 = gp[2 * 256 + tid];
        f4 t3 = gp[3 * 256 + tid];
        AM_ACC(t0, 0); t0 = gp[4 * 256 + tid];
        AM_ACC(t1, 1); t1 = gp[5 * 256 + tid];
        AM_ACC(t2, 2); t2 = gp[6 * 256 + tid];
        AM_ACC(t3, 3); t3 = gp[7 * 256 + tid];
        AM_ACC(t0, 4); AM_ACC(t1, 5); AM_ACC(t2, 6); AM_ACC(t3, 7);
#undef AM_ACC

#pragma unroll
        for (int off = 32; off > 0; off >>= 1) {
            const float ov = __shfl_down(mv, off, 64);
            const int   oi = __shfl_down(mi, off, 64);
            if (ov > mv || (ov == mv && oi < mi)) { mv = ov; mi = oi; }
        }
        if (lane == 0) { rmv[wid] = mv; rmi[wid] = mi; }
        __syncthreads();
        if (tid == 0) {
            float fmv = rmv[0];
            int   fmi = rmi[0];
#pragma unroll
            for (int k = 1; k < 4; ++k)
                if (rmv[k] > fmv || (rmv[k] == fmv && rmi[k] < fmi)) { fmv = rmv[k]; fmi = rmi[k]; }
            wsf[3 * NPART2 + b2] = fmv;
            wsi[b2]              = fmi;
        }
    }
}

__global__ __launch_bounds__(128) void dsnt_finalize(
    const float* __restrict__ wsf, const int* __restrict__ wsi,
    float* __restrict__ out)
{
    __shared__ float px[BP], py[BP], tx[BP], ty[BP];
    __shared__ float wsum[2];
    const int tid = threadIdx.x; // 0..127, one pair per thread

    {
        float s = 0.0f, sx = 0.0f, sy = 0.0f, mv = -1.0f;
        int mi = 0;
#pragma unroll
        for (int k = 0; k < SEG2; ++k) {
            const int i = tid * SEG2 + k;  // segs in ascending index order
            s  += wsf[i];
            sx += wsf[NPART2 + i];
            sy += wsf[2 * NPART2 + i];
            const float v = wsf[3 * NPART2 + i];
            const int  ii = wsi[i];
            if (v > mv || (v == mv && ii < mi)) { mv = v; mi = ii; }
        }
        px[tid] = sx / s;
        py[tid] = sy / s;
        tx[tid] = (float)((mi & 511) + 1) * (1.0f / 512.0f);
        ty[tid] = (float)((mi >> 9) + 1) * (1.0f / 512.0f);
    }
    __syncthreads();

    float term = 0.0f;
    if (tid < 64) {
        const int b = tid;
        const float px0 = px[2 * b], px1 = px[2 * b + 1];
        const float py0 = py[2 * b], py1 = py[2 * b + 1];
        const float tx0 = tx[2 * b], tx1 = tx[2 * b + 1];
        const float ty0 = ty[2 * b], ty1 = ty[2 * b + 1];

        const float ed0 = sqrtf((tx0 - px0) * (tx0 - px0) + (ty0 - py0) * (ty0 - py0));
        const float ed1 = sqrtf((tx1 - px1) * (tx1 - px1) + (ty1 - py1) * (ty1 - py1));

        const float pvx = px0 - px1, pvy = py0 - py1;
        const float tvx = tx0 - tx1, tvy = ty0 - ty1;
        const float pd = sqrtf(pvx * pvx + pvy * pvy);
        const float td = sqrtf(tvx * tvx + tvy * tvy);
        const float dot = pvx * tvx + pvy * tvy;
        const float cosd = 1.0f - cosf(dot / (pd * td));
        term = ed0 + ed1 + fabsf(pd - td) + cosd;
    }

#pragma unroll
    for (int off = 32; off > 0; off >>= 1)
        term += __shfl_down(term, off, 64);
    const int lane = tid & 63, wid = tid >> 6;
    if (lane == 0) wsum[wid] = term;
    __syncthreads();
    if (tid == 0) out[0] = (wsum[0] + wsum[1]) * (1.0f / 64.0f);
}

extern "C" void kernel_launch(void* const* d_in, const int* in_sizes, int n_in,
                              void* d_out, int out_size, void* d_ws, size_t ws_size,
                              hipStream_t stream)
{
    const float* inp = (const float*)d_in[0];
    const float* tgt = (const float*)d_in[1];
    float* out = (float*)d_out;
    float* wsf = (float*)d_ws;
    int*   wsi = (int*)((float*)d_ws + 4 * NPART2);

    dsnt_partial<<<2 * NPART2, 256, 0, stream>>>(inp, tgt, wsf, wsi);
    dsnt_finalize<<<1, 128, 0, stream>>>(wsf, wsi, out);
}